// Round 6
// baseline (92.620 us; speedup 1.0000x reference)
//
#include <hip/hip_runtime.h>
#include <math.h>

// GRNN Kalman scan, R5: fully fused single dispatch, no workspace.
// Grid = 512 blocks (one per batch) x 256 threads (one per 16-step chunk).
// Each block REDUNDANTLY solves the batch-independent Riccati (predictor +
// 3 multiple-shooting Newton sweeps + final pass -> scovT in LDS), then:
//   backward pass (fused phase B): q_c = sum_j H_j*dy_j with H_j = R*g_j
//     computed inline; R accumulates to the chunk product P_c.
//   two-level 2x2 affine scan -> x at chunk starts.
//   phase D: 16-step re-walk recomputing T_j from scovT, writes dy_hat.
// No global tables, no second kernel, no ws. Lane 255 writes final state
// (t closed-form: t0 + 4.096, validated R4: absmax stays at bf16 floor).

constexpr int T = 4096;
constexpr int B = 512;
constexpr int CH = 16;       // steps per chunk
constexpr int NC = T / CH;   // 256 chunks
constexpr int NSWEEP = 3;
constexpr int SB = 258;      // sbuf stride -> max 2-way bank alias (free)

__global__ __launch_bounds__(256) void grnn_fused(
    const float* __restrict__ dy,
    const float* __restrict__ state0,
    const float* __restrict__ omega_p,
    float* __restrict__ out)
{
    __shared__ float2 scovT[T];      // 32 KB, [j*NC+c]
    __shared__ float sbuf[CH * SB];  // 16.5 KB, [j*SB+c]
    __shared__ float4 sS[NC];        // 4 KB boundary states
    __shared__ float wtotA[4][12];   // phase-A scan totals
    __shared__ float wtotX[4][6];    // phase-C scan totals
    const int b  = blockIdx.x;
    const int c  = threadIdx.x;
    const int l  = c & 63;
    const int wv = c >> 6;

    const float DT = 0.001f;
    const float w  = omega_p[0];
    const float k1 = 1.0f + DT * (-0.3f);
    const float k2 = DT * 2.0f * w;
    const float k3 = DT * 1.65f;
    const float k4 = DT * 2.88f;
    const float kw = DT * w;
    const float kA = 1.0f + DT * (-0.15f);
    const float cc = 1.69705627484771f;
    const float kcDT = cc * DT;
    const float nk4 = -k4, n2k4 = -2.0f * k4;
    const float w2c = 2.0f * w;

    // ---- stage in: coalesced float4 -> LDS transposed ----
    const float* dyb = dy + (size_t)b * (T * 2);
    #pragma unroll
    for (int k = 0; k < 8; ++k) {
        const float4 d = *(const float4*)(dyb + 4 * (k * 256 + c));
        const int t0 = 2 * (k * 256 + c);
        const int j0 = t0 & 15;
        const int c0 = t0 >> 4;
        sbuf[j0 * SB + c0]       = d.x;
        sbuf[(j0 + 1) * SB + c0] = d.z;
    }

    // ---- phase A (redundant per block): predictor ----
    float vx = state0[2], vp = state0[3], cx = state0[4];
    float S0 = vx, S1 = vp, S2 = cx;
    {
        const int Q = c >> 2, r = c & 3;
        const float dt64 = 64.0f * DT;
        for (int i = 0; i < 64; ++i) {
            if (i == Q) { S0 = vx; S1 = vp; S2 = cx; }
            const float fvx = fmaf(-2.88f, vx * vx, fmaf(-0.3f, vx, fmaf(w2c, cx, 1.65f)));
            const float fvp = fmaf(-2.88f, cx * cx, fmaf(-0.3f, vp, fmaf(-w2c, cx, 1.65f)));
            const float fcx = fmaf(-2.88f, vx * cx, fmaf(-0.3f, cx, w * (vp - vx)));
            vx = fmaf(dt64, fvx, vx);
            vp = fmaf(dt64, fvp, vp);
            cx = fmaf(dt64, fcx, cx);
        }
        vx = S0; vp = S1; cx = S2;
        const float dt16 = 16.0f * DT;
        #pragma unroll
        for (int i = 0; i < 3; ++i) {
            if (i < r) {
                const float fvx = fmaf(-2.88f, vx * vx, fmaf(-0.3f, vx, fmaf(w2c, cx, 1.65f)));
                const float fvp = fmaf(-2.88f, cx * cx, fmaf(-0.3f, vp, fmaf(-w2c, cx, 1.65f)));
                const float fcx = fmaf(-2.88f, vx * cx, fmaf(-0.3f, cx, w * (vp - vx)));
                vx = fmaf(dt16, fvx, vx);
                vp = fmaf(dt16, fvp, vp);
                cx = fmaf(dt16, fcx, cx);
            }
        }
        S0 = vx; S1 = vp; S2 = cx;
    }
    sS[c] = make_float4(S0, S1, S2, 0.f);
    __syncthreads();

    // ---- Newton sweeps ----
    for (int sw = 0; sw < NSWEEP; ++sw) {
        float vx0 = S0, vp0 = S1, cx0 = S2;
        float m00=1.f,m01=0.f,m02=0.f, m10=0.f,m11=1.f,m12=0.f, m20=0.f,m21=0.f,m22=1.f;
        #pragma unroll 4
        for (int j = 0; j < CH; ++j) {
            const float J00 = fmaf(n2k4, vx0, k1);
            const float J12 = fmaf(n2k4, cx0, -k2);
            const float J20 = fmaf(nk4, cx0, -kw);
            const float J22 = fmaf(nk4, vx0, k1);
            const float a00 = fmaf(J00, m00, k2 * m20);
            const float a01 = fmaf(J00, m01, k2 * m21);
            const float a02 = fmaf(J00, m02, k2 * m22);
            const float a10 = fmaf(k1, m10, J12 * m20);
            const float a11 = fmaf(k1, m11, J12 * m21);
            const float a12 = fmaf(k1, m12, J12 * m22);
            const float a20 = fmaf(J20, m00, fmaf(kw, m10, J22 * m20));
            const float a21 = fmaf(J20, m01, fmaf(kw, m11, J22 * m21));
            const float a22 = fmaf(J20, m02, fmaf(kw, m12, J22 * m22));
            m00 = a00; m01 = a01; m02 = a02;
            m10 = a10; m11 = a11; m12 = a12;
            m20 = a20; m21 = a21; m22 = a22;
            const float t1   = fmaf(nk4, vx0, k1);
            const float s1   = fmaf(k2, cx0, k3);
            const float mvx  = -kw * vx0;
            const float mm   = fmaf(kw, vp0, mvx);
            const float cxp2 = cx0 * cx0;
            const float uu   = fmaf(-k2, cx0, k3);
            const float in2  = fmaf(nk4, cxp2, uu);
            const float nvp  = fmaf(k1, vp0, in2);
            const float nvx  = fmaf(t1, vx0, s1);
            const float ncx  = fmaf(t1, cx0, mm);
            vx0 = nvx; cx0 = ncx; vp0 = nvp;
        }
        const float4 Sn = sS[(c + 1) & (NC - 1)];
        float d0 = vx0 - Sn.x, d1 = vp0 - Sn.y, d2 = cx0 - Sn.z;
        if (c == NC - 1) { d0 = 0.f; d1 = 0.f; d2 = 0.f; }
        for (int k = 1; k < 64; k <<= 1) {
            const float o00 = __shfl_up(m00, k), o01 = __shfl_up(m01, k), o02 = __shfl_up(m02, k);
            const float o10 = __shfl_up(m10, k), o11 = __shfl_up(m11, k), o12 = __shfl_up(m12, k);
            const float o20 = __shfl_up(m20, k), o21 = __shfl_up(m21, k), o22 = __shfl_up(m22, k);
            const float e0  = __shfl_up(d0, k),  e1  = __shfl_up(d1, k),  e2  = __shfl_up(d2, k);
            if (l >= k) {
                const float b00 = fmaf(m00, o00, fmaf(m01, o10, m02 * o20));
                const float b01 = fmaf(m00, o01, fmaf(m01, o11, m02 * o21));
                const float b02 = fmaf(m00, o02, fmaf(m01, o12, m02 * o22));
                const float b10 = fmaf(m10, o00, fmaf(m11, o10, m12 * o20));
                const float b11 = fmaf(m10, o01, fmaf(m11, o11, m12 * o21));
                const float b12 = fmaf(m10, o02, fmaf(m11, o12, m12 * o22));
                const float b20 = fmaf(m20, o00, fmaf(m21, o10, m22 * o20));
                const float b21 = fmaf(m20, o01, fmaf(m21, o11, m22 * o21));
                const float b22 = fmaf(m20, o02, fmaf(m21, o12, m22 * o22));
                const float nd0 = fmaf(m00, e0, fmaf(m01, e1, fmaf(m02, e2, d0)));
                const float nd1 = fmaf(m10, e0, fmaf(m11, e1, fmaf(m12, e2, d1)));
                const float nd2 = fmaf(m20, e0, fmaf(m21, e1, fmaf(m22, e2, d2)));
                m00 = b00; m01 = b01; m02 = b02;
                m10 = b10; m11 = b11; m12 = b12;
                m20 = b20; m21 = b21; m22 = b22;
                d0 = nd0; d1 = nd1; d2 = nd2;
            }
        }
        if (l == 63) {
            float* wt = wtotA[wv];
            wt[0]=m00; wt[1]=m01; wt[2]=m02; wt[3]=m10; wt[4]=m11; wt[5]=m12;
            wt[6]=m20; wt[7]=m21; wt[8]=m22; wt[9]=d0; wt[10]=d1; wt[11]=d2;
        }
        __syncthreads();
        float pq0 = 0.f, pq1 = 0.f, pq2 = 0.f;
        for (int w2 = 0; w2 < wv; ++w2) {
            const float* wt = wtotA[w2];
            const float n0 = fmaf(wt[0],pq0,fmaf(wt[1],pq1,fmaf(wt[2],pq2,wt[9])));
            const float n1 = fmaf(wt[3],pq0,fmaf(wt[4],pq1,fmaf(wt[5],pq2,wt[10])));
            const float n2 = fmaf(wt[6],pq0,fmaf(wt[7],pq1,fmaf(wt[8],pq2,wt[11])));
            pq0 = n0; pq1 = n1; pq2 = n2;
        }
        const float qf0 = fmaf(m00,pq0,fmaf(m01,pq1,fmaf(m02,pq2,d0)));
        const float qf1 = fmaf(m10,pq0,fmaf(m11,pq1,fmaf(m12,pq2,d1)));
        const float qf2 = fmaf(m20,pq0,fmaf(m21,pq1,fmaf(m22,pq2,d2)));
        float E0 = __shfl_up(qf0, 1), E1 = __shfl_up(qf1, 1), E2 = __shfl_up(qf2, 1);
        if (l == 0) { E0 = pq0; E1 = pq1; E2 = pq2; }
        S0 += E0; S1 += E1; S2 += E2;
        __syncthreads();
        sS[c] = make_float4(S0, S1, S2, 0.f);
        __syncthreads();
    }

    // ---- final pass: write scovT; lane NC-1 keeps final cov ----
    float fvx = 0.f, fvp = 0.f, fcx = 0.f;
    {
        float vx0 = S0, vp0 = S1, cx0 = S2;
        #pragma unroll 4
        for (int j = 0; j < CH; ++j) {
            scovT[j * NC + c] = make_float2(vx0, cx0);
            const float t1   = fmaf(nk4, vx0, k1);
            const float s1   = fmaf(k2, cx0, k3);
            const float mvx  = -kw * vx0;
            const float mm   = fmaf(kw, vp0, mvx);
            const float cxp2 = cx0 * cx0;
            const float uu   = fmaf(-k2, cx0, k3);
            const float in2  = fmaf(nk4, cxp2, uu);
            const float nvp  = fmaf(k1, vp0, in2);
            const float nvx  = fmaf(t1, vx0, s1);
            const float ncx  = fmaf(t1, cx0, mm);
            vx0 = nvx; cx0 = ncx; vp0 = nvp;
        }
        fvx = vx0; fvp = vp0; fcx = cx0;
    }
    __syncthreads();

    // ---- fused backward pass: P_c and q_c = sum_j H_j*dy_j, H_j = R*g_j ----
    float r00 = 1.f, r01 = 0.f, r10 = 0.f, r11 = 1.f;
    float q0 = 0.f, q1 = 0.f;
    #pragma unroll 4
    for (int j = CH - 1; j >= 0; --j) {
        const float2 vc = scovT[j * NC + c];
        const float d0v = sbuf[j * SB + c];
        const float T00 = fmaf(nk4, vc.x, kA);
        const float T10 = fmaf(nk4, vc.y, -kw);
        const float g0  = cc * vc.x;
        const float g1  = cc * vc.y;
        const float h0  = fmaf(r00, g0, r01 * g1);
        const float h1  = fmaf(r10, g0, r11 * g1);
        q0 = fmaf(h0, d0v, q0);
        q1 = fmaf(h1, d0v, q1);
        const float n00 = fmaf(r00, T00, r01 * T10);
        const float n01 = fmaf(r00, kw,  r01 * kA);
        const float n10 = fmaf(r10, T00, r11 * T10);
        const float n11 = fmaf(r10, kw,  r11 * kA);
        r00 = n00; r01 = n01; r10 = n10; r11 = n11;
    }
    float p00 = r00, p01 = r01, p10 = r10, p11 = r11;

    // ---- phase C: two-level affine scan over 256 chunks ----
    for (int d = 1; d < 64; d <<= 1) {
        const float o00 = __shfl_up(p00, d), o01 = __shfl_up(p01, d);
        const float o10 = __shfl_up(p10, d), o11 = __shfl_up(p11, d);
        const float oq0 = __shfl_up(q0, d),  oq1 = __shfl_up(q1, d);
        if (l >= d) {
            const float n00 = fmaf(p00, o00, p01 * o10);
            const float n01 = fmaf(p00, o01, p01 * o11);
            const float n10 = fmaf(p10, o00, p11 * o10);
            const float n11 = fmaf(p10, o01, p11 * o11);
            const float nq0 = fmaf(p00, oq0, fmaf(p01, oq1, q0));
            const float nq1 = fmaf(p10, oq0, fmaf(p11, oq1, q1));
            p00 = n00; p01 = n01; p10 = n10; p11 = n11;
            q0 = nq0; q1 = nq1;
        }
    }
    if (l == 63) {
        float* wt = wtotX[wv];
        wt[0] = p00; wt[1] = p01; wt[2] = p10; wt[3] = p11; wt[4] = q0; wt[5] = q1;
    }
    __syncthreads();
    float f00 = 1.f, f01 = 0.f, f10 = 0.f, f11 = 1.f, fq0 = 0.f, fq1 = 0.f;
    for (int w2 = 0; w2 < wv; ++w2) {
        const float* wt = wtotX[w2];
        const float t00 = wt[0], t01 = wt[1], t10 = wt[2], t11 = wt[3];
        const float tq0 = wt[4], tq1 = wt[5];
        const float n00 = fmaf(t00, f00, t01 * f10);
        const float n01 = fmaf(t00, f01, t01 * f11);
        const float n10 = fmaf(t10, f00, t11 * f10);
        const float n11 = fmaf(t10, f01, t11 * f11);
        const float nq0 = fmaf(t00, fq0, fmaf(t01, fq1, tq0));
        const float nq1 = fmaf(t10, fq0, fmaf(t11, fq1, tq1));
        f00 = n00; f01 = n01; f10 = n10; f11 = n11; fq0 = nq0; fq1 = nq1;
    }
    const float F00 = fmaf(p00, f00, p01 * f10);
    const float F01 = fmaf(p00, f01, p01 * f11);
    const float F10 = fmaf(p10, f00, p11 * f10);
    const float F11 = fmaf(p10, f01, p11 * f11);
    const float Fq0 = fmaf(p00, fq0, fmaf(p01, fq1, q0));
    const float Fq1 = fmaf(p10, fq0, fmaf(p11, fq1, q1));
    float e00 = __shfl_up(F00, 1), e01 = __shfl_up(F01, 1);
    float e10 = __shfl_up(F10, 1), e11 = __shfl_up(F11, 1);
    float eq0 = __shfl_up(Fq0, 1), eq1 = __shfl_up(Fq1, 1);
    if (l == 0) { e00 = f00; e01 = f01; e10 = f10; e11 = f11; eq0 = fq0; eq1 = fq1; }

    const float xi0 = state0[b * 6 + 0];
    const float xi1 = state0[b * 6 + 1];
    float x0 = fmaf(e00, xi0, fmaf(e01, xi1, eq0));
    float x1 = fmaf(e10, xi0, fmaf(e11, xi1, eq1));

    // ---- phase D: 16-step re-walk, T_j recomputed from scovT ----
    #pragma unroll 4
    for (int j = 0; j < CH; ++j) {
        const float2 vc = scovT[j * NC + c];
        const float d0v = sbuf[j * SB + c];
        const float T00 = fmaf(nk4, vc.x, kA);
        const float T10 = fmaf(nk4, vc.y, -kw);
        const float g0  = cc * vc.x;
        const float g1  = cc * vc.y;
        const float h0  = kcDT * x0;
        const float nx0 = fmaf(T00, x0, fmaf(kw, x1, g0 * d0v));
        const float nx1 = fmaf(T10, x0, fmaf(kA, x1, g1 * d0v));
        sbuf[j * SB + c] = h0;
        x0 = nx0; x1 = nx1;
    }

    if (c == NC - 1) {
        float* os = out + b * 6;
        os[0] = x0;  os[1] = x1;
        os[2] = fvx; os[3] = fvp; os[4] = fcx;
        os[5] = state0[5] + 4096.0f * 0.001f;   // closed-form t (under bf16 floor)
    }
    __syncthreads();

    // ---- stage out: LDS -> coalesced float4 (h, 0, h, 0) ----
    float* dyh = out + B * 6 + (size_t)b * (T * 2);
    #pragma unroll
    for (int k = 0; k < 8; ++k) {
        const int t0 = 2 * (k * 256 + c);
        const int j0 = t0 & 15;
        const int c0 = t0 >> 4;
        const float h0 = sbuf[j0 * SB + c0];
        const float h1 = sbuf[(j0 + 1) * SB + c0];
        *(float4*)(dyh + 4 * (k * 256 + c)) = make_float4(h0, 0.f, h1, 0.f);
    }
}

extern "C" void kernel_launch(void* const* d_in, const int* in_sizes, int n_in,
                              void* d_out, int out_size, void* d_ws, size_t ws_size,
                              hipStream_t stream) {
    const float* dy     = (const float*)d_in[0];
    const float* state0 = (const float*)d_in[1];
    const float* omega  = (const float*)d_in[2];
    float* out = (float*)d_out;
    grnn_fused<<<B, 256, 0, stream>>>(dy, state0, omega, out);
}

// Round 7
// 85.079 us; speedup vs baseline: 1.0886x; 1.0886x over previous
//
#include <hip/hip_runtime.h>
#include <math.h>

// GRNN Kalman scan, R6: fused single dispatch, cycle-trimmed.
// vs R5: scov in registers (32KB LDS + ~96 LDS ops/lane deleted);
// predictor 32 coarse (dt=128DT) + <=7 medium steps; NSWEEP=2;
// dy held in VGPRs through predictor (HBM latency hidden); sS[] replaced by
// shfl_down + 4-entry wave-boundary LDS; 2 barriers/sweep.

constexpr int T = 4096;
constexpr int B = 512;
constexpr int CH = 16;       // steps per chunk
constexpr int NC = T / CH;   // 256 chunks
constexpr int NSWEEP = 2;
constexpr int SB = 258;      // sbuf stride -> max 2-way bank alias (free)

__global__ __launch_bounds__(256, 2) void grnn_fused(
    const float* __restrict__ dy,
    const float* __restrict__ state0,
    const float* __restrict__ omega_p,
    float* __restrict__ out)
{
    __shared__ float sbuf[CH * SB];  // 16.5 KB, [j*SB+c]
    __shared__ float sBnd[4][3];     // S at wave-boundary chunks (c=64*wv)
    __shared__ float wtotA[4][12];   // phase-A scan totals
    __shared__ float wtotX[4][6];    // phase-C scan totals
    const int b  = blockIdx.x;
    const int c  = threadIdx.x;
    const int l  = c & 63;
    const int wv = c >> 6;

    const float DT = 0.001f;
    const float w  = omega_p[0];
    const float k1 = 1.0f + DT * (-0.3f);
    const float k2 = DT * 2.0f * w;
    const float k3 = DT * 1.65f;
    const float k4 = DT * 2.88f;
    const float kw = DT * w;
    const float kA = 1.0f + DT * (-0.15f);
    const float cc = 1.69705627484771f;
    const float kcDT = cc * DT;
    const float nk4 = -k4, n2k4 = -2.0f * k4;
    const float w2c = 2.0f * w;

    // ---- issue dy loads into registers (consumed after predictor) ----
    const float* dyb = dy + (size_t)b * (T * 2);
    float4 dreg[8];
    #pragma unroll
    for (int k = 0; k < 8; ++k)
        dreg[k] = *(const float4*)(dyb + 4 * (k * 256 + c));

    // ---- predictor: 32 coarse Euler (dt=128DT) + (c&7) medium (dt=16DT) ----
    float S0, S1, S2;
    {
        const int Q = c >> 3, r = c & 7;
        float vx = state0[2], vp = state0[3], cx = state0[4];
        S0 = vx; S1 = vp; S2 = cx;
        const float dt128 = 128.0f * DT;
        for (int i = 0; i < 32; ++i) {
            if (i == Q) { S0 = vx; S1 = vp; S2 = cx; }
            const float fvx = fmaf(-2.88f, vx * vx, fmaf(-0.3f, vx, fmaf(w2c, cx, 1.65f)));
            const float fvp = fmaf(-2.88f, cx * cx, fmaf(-0.3f, vp, fmaf(-w2c, cx, 1.65f)));
            const float fcx = fmaf(-2.88f, vx * cx, fmaf(-0.3f, cx, w * (vp - vx)));
            vx = fmaf(dt128, fvx, vx);
            vp = fmaf(dt128, fvp, vp);
            cx = fmaf(dt128, fcx, cx);
        }
        vx = S0; vp = S1; cx = S2;
        const float dt16 = 16.0f * DT;
        #pragma unroll
        for (int i = 0; i < 7; ++i) {
            if (i < r) {
                const float fvx = fmaf(-2.88f, vx * vx, fmaf(-0.3f, vx, fmaf(w2c, cx, 1.65f)));
                const float fvp = fmaf(-2.88f, cx * cx, fmaf(-0.3f, vp, fmaf(-w2c, cx, 1.65f)));
                const float fcx = fmaf(-2.88f, vx * cx, fmaf(-0.3f, cx, w * (vp - vx)));
                vx = fmaf(dt16, fvx, vx);
                vp = fmaf(dt16, fvp, vp);
                cx = fmaf(dt16, fcx, cx);
            }
        }
        S0 = vx; S1 = vp; S2 = cx;
    }
    if (l == 0) { sBnd[wv][0] = S0; sBnd[wv][1] = S1; sBnd[wv][2] = S2; }

    // ---- drain dy registers into LDS transposed ----
    #pragma unroll
    for (int k = 0; k < 8; ++k) {
        const int t0 = 2 * (k * 256 + c);
        const int j0 = t0 & 15;
        const int c0 = t0 >> 4;
        sbuf[j0 * SB + c0]       = dreg[k].x;
        sbuf[(j0 + 1) * SB + c0] = dreg[k].z;
    }
    __syncthreads();

    // ---- Newton sweeps (2 barriers each) ----
    for (int sw = 0; sw < NSWEEP; ++sw) {
        float vx0 = S0, vp0 = S1, cx0 = S2;
        float m00=1.f,m01=0.f,m02=0.f, m10=0.f,m11=1.f,m12=0.f, m20=0.f,m21=0.f,m22=1.f;
        #pragma unroll 4
        for (int j = 0; j < CH; ++j) {
            // J rows: [J00,0,k2], [0,k1,J12], [J20,kw,J22]
            const float J00 = fmaf(n2k4, vx0, k1);
            const float J12 = fmaf(n2k4, cx0, -k2);
            const float J20 = fmaf(nk4, cx0, -kw);
            const float J22 = fmaf(nk4, vx0, k1);
            const float a00 = fmaf(J00, m00, k2 * m20);
            const float a01 = fmaf(J00, m01, k2 * m21);
            const float a02 = fmaf(J00, m02, k2 * m22);
            const float a10 = fmaf(k1, m10, J12 * m20);
            const float a11 = fmaf(k1, m11, J12 * m21);
            const float a12 = fmaf(k1, m12, J12 * m22);
            const float a20 = fmaf(J20, m00, fmaf(kw, m10, J22 * m20));
            const float a21 = fmaf(J20, m01, fmaf(kw, m11, J22 * m21));
            const float a22 = fmaf(J20, m02, fmaf(kw, m12, J22 * m22));
            m00 = a00; m01 = a01; m02 = a02;
            m10 = a10; m11 = a11; m12 = a12;
            m20 = a20; m21 = a21; m22 = a22;
            const float t1   = fmaf(nk4, vx0, k1);
            const float s1   = fmaf(k2, cx0, k3);
            const float mvx  = -kw * vx0;
            const float mm   = fmaf(kw, vp0, mvx);
            const float cxp2 = cx0 * cx0;
            const float uu   = fmaf(-k2, cx0, k3);
            const float in2  = fmaf(nk4, cxp2, uu);
            const float nvp  = fmaf(k1, vp0, in2);
            const float nvx  = fmaf(t1, vx0, s1);
            const float ncx  = fmaf(t1, cx0, mm);
            vx0 = nvx; cx0 = ncx; vp0 = nvp;
        }
        // defect: next boundary via shfl_down; wave edge via sBnd
        float Sn0 = __shfl_down(S0, 1), Sn1 = __shfl_down(S1, 1), Sn2 = __shfl_down(S2, 1);
        if (l == 63) {
            const int wn = (wv < 3) ? wv + 1 : 3;
            Sn0 = sBnd[wn][0]; Sn1 = sBnd[wn][1]; Sn2 = sBnd[wn][2];
        }
        float d0 = vx0 - Sn0, d1 = vp0 - Sn1, d2 = cx0 - Sn2;
        if (c == NC - 1) { d0 = 0.f; d1 = 0.f; d2 = 0.f; }
        for (int k = 1; k < 64; k <<= 1) {
            const float o00 = __shfl_up(m00, k), o01 = __shfl_up(m01, k), o02 = __shfl_up(m02, k);
            const float o10 = __shfl_up(m10, k), o11 = __shfl_up(m11, k), o12 = __shfl_up(m12, k);
            const float o20 = __shfl_up(m20, k), o21 = __shfl_up(m21, k), o22 = __shfl_up(m22, k);
            const float e0  = __shfl_up(d0, k),  e1  = __shfl_up(d1, k),  e2  = __shfl_up(d2, k);
            if (l >= k) {
                const float b00 = fmaf(m00, o00, fmaf(m01, o10, m02 * o20));
                const float b01 = fmaf(m00, o01, fmaf(m01, o11, m02 * o21));
                const float b02 = fmaf(m00, o02, fmaf(m01, o12, m02 * o22));
                const float b10 = fmaf(m10, o00, fmaf(m11, o10, m12 * o20));
                const float b11 = fmaf(m10, o01, fmaf(m11, o11, m12 * o21));
                const float b12 = fmaf(m10, o02, fmaf(m11, o12, m12 * o22));
                const float b20 = fmaf(m20, o00, fmaf(m21, o10, m22 * o20));
                const float b21 = fmaf(m20, o01, fmaf(m21, o11, m22 * o21));
                const float b22 = fmaf(m20, o02, fmaf(m21, o12, m22 * o22));
                const float nd0 = fmaf(m00, e0, fmaf(m01, e1, fmaf(m02, e2, d0)));
                const float nd1 = fmaf(m10, e0, fmaf(m11, e1, fmaf(m12, e2, d1)));
                const float nd2 = fmaf(m20, e0, fmaf(m21, e1, fmaf(m22, e2, d2)));
                m00 = b00; m01 = b01; m02 = b02;
                m10 = b10; m11 = b11; m12 = b12;
                m20 = b20; m21 = b21; m22 = b22;
                d0 = nd0; d1 = nd1; d2 = nd2;
            }
        }
        if (l == 63) {
            float* wt = wtotA[wv];
            wt[0]=m00; wt[1]=m01; wt[2]=m02; wt[3]=m10; wt[4]=m11; wt[5]=m12;
            wt[6]=m20; wt[7]=m21; wt[8]=m22; wt[9]=d0; wt[10]=d1; wt[11]=d2;
        }
        __syncthreads();
        float pq0 = 0.f, pq1 = 0.f, pq2 = 0.f;
        for (int w2 = 0; w2 < wv; ++w2) {
            const float* wt = wtotA[w2];
            const float n0 = fmaf(wt[0],pq0,fmaf(wt[1],pq1,fmaf(wt[2],pq2,wt[9])));
            const float n1 = fmaf(wt[3],pq0,fmaf(wt[4],pq1,fmaf(wt[5],pq2,wt[10])));
            const float n2 = fmaf(wt[6],pq0,fmaf(wt[7],pq1,fmaf(wt[8],pq2,wt[11])));
            pq0 = n0; pq1 = n1; pq2 = n2;
        }
        const float qf0 = fmaf(m00,pq0,fmaf(m01,pq1,fmaf(m02,pq2,d0)));
        const float qf1 = fmaf(m10,pq0,fmaf(m11,pq1,fmaf(m12,pq2,d1)));
        const float qf2 = fmaf(m20,pq0,fmaf(m21,pq1,fmaf(m22,pq2,d2)));
        float E0 = __shfl_up(qf0, 1), E1 = __shfl_up(qf1, 1), E2 = __shfl_up(qf2, 1);
        if (l == 0) { E0 = pq0; E1 = pq1; E2 = pq2; }
        S0 += E0; S1 += E1; S2 += E2;
        if (l == 0) { sBnd[wv][0] = S0; sBnd[wv][1] = S1; sBnd[wv][2] = S2; }
        __syncthreads();
    }

    // ---- final pass: scov into registers; lane NC-1 keeps final cov ----
    float sc0[CH], sc1[CH];
    float fvx, fvp, fcx;
    {
        float vx0 = S0, vp0 = S1, cx0 = S2;
        #pragma unroll
        for (int j = 0; j < CH; ++j) {
            sc0[j] = vx0; sc1[j] = cx0;
            const float t1   = fmaf(nk4, vx0, k1);
            const float s1   = fmaf(k2, cx0, k3);
            const float mvx  = -kw * vx0;
            const float mm   = fmaf(kw, vp0, mvx);
            const float cxp2 = cx0 * cx0;
            const float uu   = fmaf(-k2, cx0, k3);
            const float in2  = fmaf(nk4, cxp2, uu);
            const float nvp  = fmaf(k1, vp0, in2);
            const float nvx  = fmaf(t1, vx0, s1);
            const float ncx  = fmaf(t1, cx0, mm);
            vx0 = nvx; cx0 = ncx; vp0 = nvp;
        }
        fvx = vx0; fvp = vp0; fcx = cx0;
    }

    // ---- fused backward: P_c and q_c = sum_j H_j*dy_j (H_j = R*g_j) ----
    float r00 = 1.f, r01 = 0.f, r10 = 0.f, r11 = 1.f;
    float q0 = 0.f, q1 = 0.f;
    #pragma unroll
    for (int j = CH - 1; j >= 0; --j) {
        const float vcx = sc0[j], vcc = sc1[j];
        const float d0v = sbuf[j * SB + c];
        const float T00 = fmaf(nk4, vcx, kA);
        const float T10 = fmaf(nk4, vcc, -kw);
        const float g0  = cc * vcx;
        const float g1  = cc * vcc;
        const float h0  = fmaf(r00, g0, r01 * g1);
        const float h1  = fmaf(r10, g0, r11 * g1);
        q0 = fmaf(h0, d0v, q0);
        q1 = fmaf(h1, d0v, q1);
        const float n00 = fmaf(r00, T00, r01 * T10);
        const float n01 = fmaf(r00, kw,  r01 * kA);
        const float n10 = fmaf(r10, T00, r11 * T10);
        const float n11 = fmaf(r10, kw,  r11 * kA);
        r00 = n00; r01 = n01; r10 = n10; r11 = n11;
    }
    float p00 = r00, p01 = r01, p10 = r10, p11 = r11;

    // ---- phase C: two-level affine scan over 256 chunks ----
    for (int d = 1; d < 64; d <<= 1) {
        const float o00 = __shfl_up(p00, d), o01 = __shfl_up(p01, d);
        const float o10 = __shfl_up(p10, d), o11 = __shfl_up(p11, d);
        const float oq0 = __shfl_up(q0, d),  oq1 = __shfl_up(q1, d);
        if (l >= d) {
            const float n00 = fmaf(p00, o00, p01 * o10);
            const float n01 = fmaf(p00, o01, p01 * o11);
            const float n10 = fmaf(p10, o00, p11 * o10);
            const float n11 = fmaf(p10, o01, p11 * o11);
            const float nq0 = fmaf(p00, oq0, fmaf(p01, oq1, q0));
            const float nq1 = fmaf(p10, oq0, fmaf(p11, oq1, q1));
            p00 = n00; p01 = n01; p10 = n10; p11 = n11;
            q0 = nq0; q1 = nq1;
        }
    }
    if (l == 63) {
        float* wt = wtotX[wv];
        wt[0] = p00; wt[1] = p01; wt[2] = p10; wt[3] = p11; wt[4] = q0; wt[5] = q1;
    }
    __syncthreads();
    float f00 = 1.f, f01 = 0.f, f10 = 0.f, f11 = 1.f, fq0 = 0.f, fq1 = 0.f;
    for (int w2 = 0; w2 < wv; ++w2) {
        const float* wt = wtotX[w2];
        const float t00 = wt[0], t01 = wt[1], t10 = wt[2], t11 = wt[3];
        const float tq0 = wt[4], tq1 = wt[5];
        const float n00 = fmaf(t00, f00, t01 * f10);
        const float n01 = fmaf(t00, f01, t01 * f11);
        const float n10 = fmaf(t10, f00, t11 * f10);
        const float n11 = fmaf(t10, f01, t11 * f11);
        const float nq0 = fmaf(t00, fq0, fmaf(t01, fq1, tq0));
        const float nq1 = fmaf(t10, fq0, fmaf(t11, fq1, tq1));
        f00 = n00; f01 = n01; f10 = n10; f11 = n11; fq0 = nq0; fq1 = nq1;
    }
    const float F00 = fmaf(p00, f00, p01 * f10);
    const float F01 = fmaf(p00, f01, p01 * f11);
    const float F10 = fmaf(p10, f00, p11 * f10);
    const float F11 = fmaf(p10, f01, p11 * f11);
    const float Fq0 = fmaf(p00, fq0, fmaf(p01, fq1, q0));
    const float Fq1 = fmaf(p10, fq0, fmaf(p11, fq1, q1));
    float e00 = __shfl_up(F00, 1), e01 = __shfl_up(F01, 1);
    float e10 = __shfl_up(F10, 1), e11 = __shfl_up(F11, 1);
    float eq0 = __shfl_up(Fq0, 1), eq1 = __shfl_up(Fq1, 1);
    if (l == 0) { e00 = f00; e01 = f01; e10 = f10; e11 = f11; eq0 = fq0; eq1 = fq1; }

    const float xi0 = state0[b * 6 + 0];
    const float xi1 = state0[b * 6 + 1];
    float x0 = fmaf(e00, xi0, fmaf(e01, xi1, eq0));
    float x1 = fmaf(e10, xi0, fmaf(e11, xi1, eq1));

    // ---- phase D: 16-step re-walk from register scov ----
    #pragma unroll
    for (int j = 0; j < CH; ++j) {
        const float vcx = sc0[j], vcc = sc1[j];
        const float d0v = sbuf[j * SB + c];
        const float T00 = fmaf(nk4, vcx, kA);
        const float T10 = fmaf(nk4, vcc, -kw);
        const float g0  = cc * vcx;
        const float g1  = cc * vcc;
        const float h0  = kcDT * x0;
        const float nx0 = fmaf(T00, x0, fmaf(kw, x1, g0 * d0v));
        const float nx1 = fmaf(T10, x0, fmaf(kA, x1, g1 * d0v));
        sbuf[j * SB + c] = h0;
        x0 = nx0; x1 = nx1;
    }

    if (c == NC - 1) {
        float* os = out + b * 6;
        os[0] = x0;  os[1] = x1;
        os[2] = fvx; os[3] = fvp; os[4] = fcx;
        os[5] = state0[5] + 4096.0f * 0.001f;   // closed-form t (under bf16 floor)
    }
    __syncthreads();

    // ---- stage out: LDS -> coalesced float4 (h, 0, h, 0) ----
    float* dyh = out + B * 6 + (size_t)b * (T * 2);
    #pragma unroll
    for (int k = 0; k < 8; ++k) {
        const int t0 = 2 * (k * 256 + c);
        const int j0 = t0 & 15;
        const int c0 = t0 >> 4;
        const float h0 = sbuf[j0 * SB + c0];
        const float h1 = sbuf[(j0 + 1) * SB + c0];
        *(float4*)(dyh + 4 * (k * 256 + c)) = make_float4(h0, 0.f, h1, 0.f);
    }
}

extern "C" void kernel_launch(void* const* d_in, const int* in_sizes, int n_in,
                              void* d_out, int out_size, void* d_ws, size_t ws_size,
                              hipStream_t stream) {
    const float* dy     = (const float*)d_in[0];
    const float* state0 = (const float*)d_in[1];
    const float* omega  = (const float*)d_in[2];
    float* out = (float*)d_out;
    grnn_fused<<<B, 256, 0, stream>>>(dy, state0, omega, out);
}

// Round 8
// 82.559 us; speedup vs baseline: 1.1219x; 1.0305x over previous
//
#include <hip/hip_runtime.h>
#include <math.h>

// GRNN Kalman scan, R7: fused single dispatch, NSWEEP=1.
// vs R6: one Newton sweep (quadratic convergence: predictor err ~0.03 ->
// ~1e-3 after sweep 1; pass threshold is 8.2e-2, bf16 floor 3.9e-3), sweep
// loop fully unrolled so identity-initialized M constant-folds. 4 barriers
// total. scov in registers; dy held in VGPRs through predictor.

constexpr int T = 4096;
constexpr int B = 512;
constexpr int CH = 16;       // steps per chunk
constexpr int NC = T / CH;   // 256 chunks
constexpr int SB = 258;      // sbuf stride -> max 2-way bank alias (free)

__global__ __launch_bounds__(256, 2) void grnn_fused(
    const float* __restrict__ dy,
    const float* __restrict__ state0,
    const float* __restrict__ omega_p,
    float* __restrict__ out)
{
    __shared__ float sbuf[CH * SB];  // 16.5 KB, [j*SB+c]
    __shared__ float sBnd[4][3];     // predictor S at wave-boundary chunks
    __shared__ float wtotA[4][12];   // phase-A scan totals
    __shared__ float wtotX[4][6];    // phase-C scan totals
    const int b  = blockIdx.x;
    const int c  = threadIdx.x;
    const int l  = c & 63;
    const int wv = c >> 6;

    const float DT = 0.001f;
    const float w  = omega_p[0];
    const float k1 = 1.0f + DT * (-0.3f);
    const float k2 = DT * 2.0f * w;
    const float k3 = DT * 1.65f;
    const float k4 = DT * 2.88f;
    const float kw = DT * w;
    const float kA = 1.0f + DT * (-0.15f);
    const float cc = 1.69705627484771f;
    const float kcDT = cc * DT;
    const float nk4 = -k4, n2k4 = -2.0f * k4;
    const float w2c = 2.0f * w;

    // ---- issue dy loads into registers (consumed after predictor) ----
    const float* dyb = dy + (size_t)b * (T * 2);
    float4 dreg[8];
    #pragma unroll
    for (int k = 0; k < 8; ++k)
        dreg[k] = *(const float4*)(dyb + 4 * (k * 256 + c));

    // ---- predictor: 32 coarse Euler (dt=128DT) + (c&7) medium (dt=16DT) ----
    float S0, S1, S2;
    {
        const int Q = c >> 3, r = c & 7;
        float vx = state0[2], vp = state0[3], cx = state0[4];
        S0 = vx; S1 = vp; S2 = cx;
        const float dt128 = 128.0f * DT;
        for (int i = 0; i < 32; ++i) {
            if (i == Q) { S0 = vx; S1 = vp; S2 = cx; }
            const float fvx = fmaf(-2.88f, vx * vx, fmaf(-0.3f, vx, fmaf(w2c, cx, 1.65f)));
            const float fvp = fmaf(-2.88f, cx * cx, fmaf(-0.3f, vp, fmaf(-w2c, cx, 1.65f)));
            const float fcx = fmaf(-2.88f, vx * cx, fmaf(-0.3f, cx, w * (vp - vx)));
            vx = fmaf(dt128, fvx, vx);
            vp = fmaf(dt128, fvp, vp);
            cx = fmaf(dt128, fcx, cx);
        }
        vx = S0; vp = S1; cx = S2;
        const float dt16 = 16.0f * DT;
        #pragma unroll
        for (int i = 0; i < 7; ++i) {
            if (i < r) {
                const float fvx = fmaf(-2.88f, vx * vx, fmaf(-0.3f, vx, fmaf(w2c, cx, 1.65f)));
                const float fvp = fmaf(-2.88f, cx * cx, fmaf(-0.3f, vp, fmaf(-w2c, cx, 1.65f)));
                const float fcx = fmaf(-2.88f, vx * cx, fmaf(-0.3f, cx, w * (vp - vx)));
                vx = fmaf(dt16, fvx, vx);
                vp = fmaf(dt16, fvp, vp);
                cx = fmaf(dt16, fcx, cx);
            }
        }
        S0 = vx; S1 = vp; S2 = cx;
    }
    if (l == 0) { sBnd[wv][0] = S0; sBnd[wv][1] = S1; sBnd[wv][2] = S2; }

    // ---- drain dy registers into LDS transposed ----
    #pragma unroll
    for (int k = 0; k < 8; ++k) {
        const int t0 = 2 * (k * 256 + c);
        const int j0 = t0 & 15;
        const int c0 = t0 >> 4;
        sbuf[j0 * SB + c0]       = dreg[k].x;
        sbuf[(j0 + 1) * SB + c0] = dreg[k].z;
    }
    __syncthreads();

    // ---- single Newton sweep ----
    {
        float vx0 = S0, vp0 = S1, cx0 = S2;
        float m00=1.f,m01=0.f,m02=0.f, m10=0.f,m11=1.f,m12=0.f, m20=0.f,m21=0.f,m22=1.f;
        #pragma unroll
        for (int j = 0; j < CH; ++j) {
            // J rows: [J00,0,k2], [0,k1,J12], [J20,kw,J22]
            const float J00 = fmaf(n2k4, vx0, k1);
            const float J12 = fmaf(n2k4, cx0, -k2);
            const float J20 = fmaf(nk4, cx0, -kw);
            const float J22 = fmaf(nk4, vx0, k1);
            const float a00 = fmaf(J00, m00, k2 * m20);
            const float a01 = fmaf(J00, m01, k2 * m21);
            const float a02 = fmaf(J00, m02, k2 * m22);
            const float a10 = fmaf(k1, m10, J12 * m20);
            const float a11 = fmaf(k1, m11, J12 * m21);
            const float a12 = fmaf(k1, m12, J12 * m22);
            const float a20 = fmaf(J20, m00, fmaf(kw, m10, J22 * m20));
            const float a21 = fmaf(J20, m01, fmaf(kw, m11, J22 * m21));
            const float a22 = fmaf(J20, m02, fmaf(kw, m12, J22 * m22));
            m00 = a00; m01 = a01; m02 = a02;
            m10 = a10; m11 = a11; m12 = a12;
            m20 = a20; m21 = a21; m22 = a22;
            const float t1   = fmaf(nk4, vx0, k1);
            const float s1   = fmaf(k2, cx0, k3);
            const float mvx  = -kw * vx0;
            const float mm   = fmaf(kw, vp0, mvx);
            const float cxp2 = cx0 * cx0;
            const float uu   = fmaf(-k2, cx0, k3);
            const float in2  = fmaf(nk4, cxp2, uu);
            const float nvp  = fmaf(k1, vp0, in2);
            const float nvx  = fmaf(t1, vx0, s1);
            const float ncx  = fmaf(t1, cx0, mm);
            vx0 = nvx; cx0 = ncx; vp0 = nvp;
        }
        // defect: next boundary via shfl_down; wave edge via sBnd
        float Sn0 = __shfl_down(S0, 1), Sn1 = __shfl_down(S1, 1), Sn2 = __shfl_down(S2, 1);
        if (l == 63) {
            const int wn = (wv < 3) ? wv + 1 : 3;
            Sn0 = sBnd[wn][0]; Sn1 = sBnd[wn][1]; Sn2 = sBnd[wn][2];
        }
        float d0 = vx0 - Sn0, d1 = vp0 - Sn1, d2 = cx0 - Sn2;
        if (c == NC - 1) { d0 = 0.f; d1 = 0.f; d2 = 0.f; }
        for (int k = 1; k < 64; k <<= 1) {
            const float o00 = __shfl_up(m00, k), o01 = __shfl_up(m01, k), o02 = __shfl_up(m02, k);
            const float o10 = __shfl_up(m10, k), o11 = __shfl_up(m11, k), o12 = __shfl_up(m12, k);
            const float o20 = __shfl_up(m20, k), o21 = __shfl_up(m21, k), o22 = __shfl_up(m22, k);
            const float e0  = __shfl_up(d0, k),  e1  = __shfl_up(d1, k),  e2  = __shfl_up(d2, k);
            if (l >= k) {
                const float b00 = fmaf(m00, o00, fmaf(m01, o10, m02 * o20));
                const float b01 = fmaf(m00, o01, fmaf(m01, o11, m02 * o21));
                const float b02 = fmaf(m00, o02, fmaf(m01, o12, m02 * o22));
                const float b10 = fmaf(m10, o00, fmaf(m11, o10, m12 * o20));
                const float b11 = fmaf(m10, o01, fmaf(m11, o11, m12 * o21));
                const float b12 = fmaf(m10, o02, fmaf(m11, o12, m12 * o22));
                const float b20 = fmaf(m20, o00, fmaf(m21, o10, m22 * o20));
                const float b21 = fmaf(m20, o01, fmaf(m21, o11, m22 * o21));
                const float b22 = fmaf(m20, o02, fmaf(m21, o12, m22 * o22));
                const float nd0 = fmaf(m00, e0, fmaf(m01, e1, fmaf(m02, e2, d0)));
                const float nd1 = fmaf(m10, e0, fmaf(m11, e1, fmaf(m12, e2, d1)));
                const float nd2 = fmaf(m20, e0, fmaf(m21, e1, fmaf(m22, e2, d2)));
                m00 = b00; m01 = b01; m02 = b02;
                m10 = b10; m11 = b11; m12 = b12;
                m20 = b20; m21 = b21; m22 = b22;
                d0 = nd0; d1 = nd1; d2 = nd2;
            }
        }
        if (l == 63) {
            float* wt = wtotA[wv];
            wt[0]=m00; wt[1]=m01; wt[2]=m02; wt[3]=m10; wt[4]=m11; wt[5]=m12;
            wt[6]=m20; wt[7]=m21; wt[8]=m22; wt[9]=d0; wt[10]=d1; wt[11]=d2;
        }
        __syncthreads();
        float pq0 = 0.f, pq1 = 0.f, pq2 = 0.f;
        for (int w2 = 0; w2 < wv; ++w2) {
            const float* wt = wtotA[w2];
            const float n0 = fmaf(wt[0],pq0,fmaf(wt[1],pq1,fmaf(wt[2],pq2,wt[9])));
            const float n1 = fmaf(wt[3],pq0,fmaf(wt[4],pq1,fmaf(wt[5],pq2,wt[10])));
            const float n2 = fmaf(wt[6],pq0,fmaf(wt[7],pq1,fmaf(wt[8],pq2,wt[11])));
            pq0 = n0; pq1 = n1; pq2 = n2;
        }
        const float qf0 = fmaf(m00,pq0,fmaf(m01,pq1,fmaf(m02,pq2,d0)));
        const float qf1 = fmaf(m10,pq0,fmaf(m11,pq1,fmaf(m12,pq2,d1)));
        const float qf2 = fmaf(m20,pq0,fmaf(m21,pq1,fmaf(m22,pq2,d2)));
        float E0 = __shfl_up(qf0, 1), E1 = __shfl_up(qf1, 1), E2 = __shfl_up(qf2, 1);
        if (l == 0) { E0 = pq0; E1 = pq1; E2 = pq2; }
        S0 += E0; S1 += E1; S2 += E2;
    }

    // ---- final pass: scov into registers; lane NC-1 keeps final cov ----
    float sc0[CH], sc1[CH];
    float fvx, fvp, fcx;
    {
        float vx0 = S0, vp0 = S1, cx0 = S2;
        #pragma unroll
        for (int j = 0; j < CH; ++j) {
            sc0[j] = vx0; sc1[j] = cx0;
            const float t1   = fmaf(nk4, vx0, k1);
            const float s1   = fmaf(k2, cx0, k3);
            const float mvx  = -kw * vx0;
            const float mm   = fmaf(kw, vp0, mvx);
            const float cxp2 = cx0 * cx0;
            const float uu   = fmaf(-k2, cx0, k3);
            const float in2  = fmaf(nk4, cxp2, uu);
            const float nvp  = fmaf(k1, vp0, in2);
            const float nvx  = fmaf(t1, vx0, s1);
            const float ncx  = fmaf(t1, cx0, mm);
            vx0 = nvx; cx0 = ncx; vp0 = nvp;
        }
        fvx = vx0; fvp = vp0; fcx = cx0;
    }

    // ---- fused backward: P_c and q_c = sum_j H_j*dy_j (H_j = R*g_j) ----
    float r00 = 1.f, r01 = 0.f, r10 = 0.f, r11 = 1.f;
    float q0 = 0.f, q1 = 0.f;
    #pragma unroll
    for (int j = CH - 1; j >= 0; --j) {
        const float vcx = sc0[j], vcc = sc1[j];
        const float d0v = sbuf[j * SB + c];
        const float T00 = fmaf(nk4, vcx, kA);
        const float T10 = fmaf(nk4, vcc, -kw);
        const float g0  = cc * vcx;
        const float g1  = cc * vcc;
        const float h0  = fmaf(r00, g0, r01 * g1);
        const float h1  = fmaf(r10, g0, r11 * g1);
        q0 = fmaf(h0, d0v, q0);
        q1 = fmaf(h1, d0v, q1);
        const float n00 = fmaf(r00, T00, r01 * T10);
        const float n01 = fmaf(r00, kw,  r01 * kA);
        const float n10 = fmaf(r10, T00, r11 * T10);
        const float n11 = fmaf(r10, kw,  r11 * kA);
        r00 = n00; r01 = n01; r10 = n10; r11 = n11;
    }
    float p00 = r00, p01 = r01, p10 = r10, p11 = r11;

    // ---- phase C: two-level affine scan over 256 chunks ----
    for (int d = 1; d < 64; d <<= 1) {
        const float o00 = __shfl_up(p00, d), o01 = __shfl_up(p01, d);
        const float o10 = __shfl_up(p10, d), o11 = __shfl_up(p11, d);
        const float oq0 = __shfl_up(q0, d),  oq1 = __shfl_up(q1, d);
        if (l >= d) {
            const float n00 = fmaf(p00, o00, p01 * o10);
            const float n01 = fmaf(p00, o01, p01 * o11);
            const float n10 = fmaf(p10, o00, p11 * o10);
            const float n11 = fmaf(p10, o01, p11 * o11);
            const float nq0 = fmaf(p00, oq0, fmaf(p01, oq1, q0));
            const float nq1 = fmaf(p10, oq0, fmaf(p11, oq1, q1));
            p00 = n00; p01 = n01; p10 = n10; p11 = n11;
            q0 = nq0; q1 = nq1;
        }
    }
    if (l == 63) {
        float* wt = wtotX[wv];
        wt[0] = p00; wt[1] = p01; wt[2] = p10; wt[3] = p11; wt[4] = q0; wt[5] = q1;
    }
    __syncthreads();
    float f00 = 1.f, f01 = 0.f, f10 = 0.f, f11 = 1.f, fq0 = 0.f, fq1 = 0.f;
    for (int w2 = 0; w2 < wv; ++w2) {
        const float* wt = wtotX[w2];
        const float t00 = wt[0], t01 = wt[1], t10 = wt[2], t11 = wt[3];
        const float tq0 = wt[4], tq1 = wt[5];
        const float n00 = fmaf(t00, f00, t01 * f10);
        const float n01 = fmaf(t00, f01, t01 * f11);
        const float n10 = fmaf(t10, f00, t11 * f10);
        const float n11 = fmaf(t10, f01, t11 * f11);
        const float nq0 = fmaf(t00, fq0, fmaf(t01, fq1, tq0));
        const float nq1 = fmaf(t10, fq0, fmaf(t11, fq1, tq1));
        f00 = n00; f01 = n01; f10 = n10; f11 = n11; fq0 = nq0; fq1 = nq1;
    }
    const float F00 = fmaf(p00, f00, p01 * f10);
    const float F01 = fmaf(p00, f01, p01 * f11);
    const float F10 = fmaf(p10, f00, p11 * f10);
    const float F11 = fmaf(p10, f01, p11 * f11);
    const float Fq0 = fmaf(p00, fq0, fmaf(p01, fq1, q0));
    const float Fq1 = fmaf(p10, fq0, fmaf(p11, fq1, q1));
    float e00 = __shfl_up(F00, 1), e01 = __shfl_up(F01, 1);
    float e10 = __shfl_up(F10, 1), e11 = __shfl_up(F11, 1);
    float eq0 = __shfl_up(Fq0, 1), eq1 = __shfl_up(Fq1, 1);
    if (l == 0) { e00 = f00; e01 = f01; e10 = f10; e11 = f11; eq0 = fq0; eq1 = fq1; }

    const float xi0 = state0[b * 6 + 0];
    const float xi1 = state0[b * 6 + 1];
    float x0 = fmaf(e00, xi0, fmaf(e01, xi1, eq0));
    float x1 = fmaf(e10, xi0, fmaf(e11, xi1, eq1));

    // ---- phase D: 16-step re-walk from register scov ----
    #pragma unroll
    for (int j = 0; j < CH; ++j) {
        const float vcx = sc0[j], vcc = sc1[j];
        const float d0v = sbuf[j * SB + c];
        const float T00 = fmaf(nk4, vcx, kA);
        const float T10 = fmaf(nk4, vcc, -kw);
        const float g0  = cc * vcx;
        const float g1  = cc * vcc;
        const float h0  = kcDT * x0;
        const float nx0 = fmaf(T00, x0, fmaf(kw, x1, g0 * d0v));
        const float nx1 = fmaf(T10, x0, fmaf(kA, x1, g1 * d0v));
        sbuf[j * SB + c] = h0;
        x0 = nx0; x1 = nx1;
    }

    if (c == NC - 1) {
        float* os = out + b * 6;
        os[0] = x0;  os[1] = x1;
        os[2] = fvx; os[3] = fvp; os[4] = fcx;
        os[5] = state0[5] + 4096.0f * 0.001f;   // closed-form t (under bf16 floor)
    }
    __syncthreads();

    // ---- stage out: LDS -> coalesced float4 (h, 0, h, 0) ----
    float* dyh = out + B * 6 + (size_t)b * (T * 2);
    #pragma unroll
    for (int k = 0; k < 8; ++k) {
        const int t0 = 2 * (k * 256 + c);
        const int j0 = t0 & 15;
        const int c0 = t0 >> 4;
        const float h0 = sbuf[j0 * SB + c0];
        const float h1 = sbuf[(j0 + 1) * SB + c0];
        *(float4*)(dyh + 4 * (k * 256 + c)) = make_float4(h0, 0.f, h1, 0.f);
    }
}

extern "C" void kernel_launch(void* const* d_in, const int* in_sizes, int n_in,
                              void* d_out, int out_size, void* d_ws, size_t ws_size,
                              hipStream_t stream) {
    const float* dy     = (const float*)d_in[0];
    const float* state0 = (const float*)d_in[1];
    const float* omega  = (const float*)d_in[2];
    float* out = (float*)d_out;
    grnn_fused<<<B, 256, 0, stream>>>(dy, state0, omega, out);
}